// Round 1
// baseline (1537.823 us; speedup 1.0000x reference)
//
#include <hip/hip_runtime.h>
#include <hip/hip_bf16.h>

typedef unsigned short u16;
typedef __bf16 bf16x8 __attribute__((ext_vector_type(8)));
typedef float f32x4 __attribute__((ext_vector_type(4)));

#define Bn 1024
#define Cn 2048
#define Hn 32
#define Nn 64
static const size_t BC = (size_t)Bn * Cn;   // 2097152
static const size_t CC = (size_t)Cn * Cn;   // 4194304

// ---------- helpers ----------
__device__ __forceinline__ void splitf(float x, u16& hi, u16& lo) {
    unsigned xb = __builtin_bit_cast(unsigned, x);
    u16 h = (u16)(xb >> 16);                       // truncate to bf16
    float hf = __builtin_bit_cast(float, (unsigned)h << 16);
    float l = x - hf;                              // exact residual
    u16 lw = (u16)(__builtin_bit_cast(unsigned, l) >> 16);
    hi = h; lo = lw;
}

__device__ __forceinline__ void gl_lds16(const void* g, void* l) {
    __builtin_amdgcn_global_load_lds(
        (__attribute__((address_space(1))) void*)(unsigned long long)g,
        (__attribute__((address_space(3))) void*)l, 16, 0, 0);
}

// ---------- kernel 1: prep (xz, maa MLP, x5, decay MLP, new_shifted) ----------
// grid 256 blocks, 4 rows/block, 256 threads
__global__ __launch_bounds__(256) void k_prep(
    const float* __restrict__ inputs, const float* __restrict__ shifted,
    const float* __restrict__ tmx, const float* __restrict__ w1,
    const float* __restrict__ w2, const float* __restrict__ wkvrg,
    const float* __restrict__ tdw1, const float* __restrict__ tdw2,
    const float* __restrict__ tdp, float* __restrict__ new_shifted,
    u16* __restrict__ Ahi, u16* __restrict__ Alo, float* __restrict__ wdec)
{
    __shared__ float xz[4][2048];      // reused as x5[0] later
    __shared__ float yb[4][160];
    __shared__ float pt[8][4][32];
    __shared__ float zz[4][32];
    const int t = threadIdx.x;
    const int row0 = blockIdx.x * 4;

    // phase 0: xz = x + (shifted-x)*tmx ; new_shifted = x
    for (int r = 0; r < 4; ++r) {
        const float* xr = inputs + (size_t)(row0 + r) * Cn;
        const float* sr = shifted + (size_t)(row0 + r) * Cn;
        float* nsr = new_shifted + (size_t)(row0 + r) * Cn;
        for (int c = t; c < Cn; c += 256) {
            float x = xr[c], sh = sr[c];
            nsr[c] = x;
            xz[r][c] = x + (sh - x) * tmx[c];
        }
    }
    __syncthreads();

    // phase 1: y = tanh(xz @ w1)   (160 outputs per row)
    if (t < 160) {
        float a0 = 0, a1 = 0, a2 = 0, a3 = 0;
        for (int c = 0; c < Cn; ++c) {
            float wv = w1[c * 160 + t];
            a0 += xz[0][c] * wv; a1 += xz[1][c] * wv;
            a2 += xz[2][c] * wv; a3 += xz[3][c] * wv;
        }
        yb[0][t] = tanhf(a0); yb[1][t] = tanhf(a1);
        yb[2][t] = tanhf(a2); yb[3][t] = tanhf(a3);
    }
    __syncthreads();

    // phase 2: x5[f] = x + xx*(wkvrg[f] + y[f] @ w2[f]); f=0 -> LDS, f>=1 -> bf16 hi/lo
    for (int f = 0; f < 5; ++f) {
        for (int g = 0; g < 8; ++g) {
            const int c = g * 256 + t;
            float a0 = 0, a1 = 0, a2 = 0, a3 = 0;
            const float* w2p = w2 + (size_t)f * 32 * Cn + c;
            #pragma unroll 8
            for (int e = 0; e < 32; ++e) {
                float wv = w2p[(size_t)e * Cn];
                float y0 = yb[0][f * 32 + e], y1 = yb[1][f * 32 + e];
                float y2 = yb[2][f * 32 + e], y3 = yb[3][f * 32 + e];
                a0 += y0 * wv; a1 += y1 * wv; a2 += y2 * wv; a3 += y3 * wv;
            }
            const float wk = wkvrg[f * Cn + c];
            float accs[4] = {a0, a1, a2, a3};
            #pragma unroll
            for (int r = 0; r < 4; ++r) {
                float x  = inputs[(size_t)(row0 + r) * Cn + c];
                float xx = shifted[(size_t)(row0 + r) * Cn + c] - x;
                float x5 = x + xx * (wk + accs[r]);
                if (f == 0) {
                    xz[r][c] = x5;
                } else {
                    u16 h, l; splitf(x5, h, l);
                    size_t off = (size_t)(f - 1) * BC + (size_t)(row0 + r) * Cn + c;
                    Ahi[off] = h; Alo[off] = l;
                }
            }
        }
    }
    __syncthreads();

    // phase 3: z = tanh(x5[0] @ tdw1)   (32 outputs per row)
    {
        const int j = t & 31, g = t >> 5;
        float a0 = 0, a1 = 0, a2 = 0, a3 = 0;
        const int cbeg = g * 256;
        for (int c = cbeg; c < cbeg + 256; ++c) {
            float wv = tdw1[c * 32 + j];
            a0 += xz[0][c] * wv; a1 += xz[1][c] * wv;
            a2 += xz[2][c] * wv; a3 += xz[3][c] * wv;
        }
        pt[g][0][j] = a0; pt[g][1][j] = a1; pt[g][2][j] = a2; pt[g][3][j] = a3;
    }
    __syncthreads();
    if (t < 128) {
        const int r = t >> 5, j = t & 31;
        float s = 0;
        #pragma unroll
        for (int g = 0; g < 8; ++g) s += pt[g][r][j];
        zz[r][j] = tanhf(s);
    }
    __syncthreads();

    // phase 4: w = exp(-exp(z @ tdw2 + tdp))
    for (int g = 0; g < 8; ++g) {
        const int c = g * 256 + t;
        float a0 = 0, a1 = 0, a2 = 0, a3 = 0;
        #pragma unroll 8
        for (int j = 0; j < 32; ++j) {
            float wv = tdw2[j * Cn + c];
            a0 += zz[0][j] * wv; a1 += zz[1][j] * wv;
            a2 += zz[2][j] * wv; a3 += zz[3][j] * wv;
        }
        float tp = tdp[c];
        wdec[(size_t)(row0 + 0) * Cn + c] = expf(-expf(a0 + tp));
        wdec[(size_t)(row0 + 1) * Cn + c] = expf(-expf(a1 + tp));
        wdec[(size_t)(row0 + 2) * Cn + c] = expf(-expf(a2 + tp));
        wdec[(size_t)(row0 + 3) * Cn + c] = expf(-expf(a3 + tp));
    }
}

// ---------- kernel 2: W (K,N) -> W^T (N,K) split into bf16 hi/lo ----------
// grid (64,64), block (32,8)
__global__ __launch_bounds__(256) void k_transpose_split(
    const float* __restrict__ W, u16* __restrict__ Thi, u16* __restrict__ Tlo)
{
    __shared__ float tile[32][33];
    const int tx = threadIdx.x, ty = threadIdx.y;
    const int k0 = blockIdx.x * 32, n0 = blockIdx.y * 32;
    #pragma unroll
    for (int i = 0; i < 4; ++i) {
        int kk = ty + i * 8;
        tile[kk][tx] = W[(size_t)(k0 + kk) * Cn + n0 + tx];
    }
    __syncthreads();
    #pragma unroll
    for (int i = 0; i < 4; ++i) {
        int nn = ty + i * 8;
        float v = tile[tx][nn];          // = W[k0+tx][n0+nn]
        u16 h, l; splitf(v, h, l);
        size_t off = (size_t)(n0 + nn) * Cn + k0 + tx;
        Thi[off] = h; Tlo[off] = l;
    }
}

// ---------- kernel 3: split-bf16 MFMA GEMM, 128x128 tile, BK=32 ----------
// C[M=1024][N=2048] = A[M][K] * B[K][N], B given transposed (WT[N][K]); z batches
__global__ __launch_bounds__(256) void k_gemm(
    const u16* __restrict__ Ahi, const u16* __restrict__ Alo,
    const u16* __restrict__ Bhi, const u16* __restrict__ Blo,
    float* __restrict__ Cout,
    unsigned long long strideA, unsigned long long strideB, unsigned long long strideC)
{
    __shared__ __align__(16) unsigned char sm[32768];  // 4 tiles x [128][32] bf16
    const unsigned long long z = blockIdx.z;
    Ahi += z * strideA; Alo += z * strideA;
    Bhi += z * strideB; Blo += z * strideB;
    Cout += z * strideC;

    const int t = threadIdx.x;
    const int row0 = blockIdx.y * 128;
    const int col0 = blockIdx.x * 128;
    const int lane = t & 63, wave = t >> 6;
    const int wr = (wave >> 1) * 64, wc = (wave & 1) * 64;
    const int fr = lane & 15;
    const int kb = (lane >> 4) * 16;   // byte offset of this lane's 8-elem k-group

    f32x4 acc[4][4];
    #pragma unroll
    for (int m = 0; m < 4; ++m)
        #pragma unroll
        for (int n = 0; n < 4; ++n) { f32x4 zv = {0.f, 0.f, 0.f, 0.f}; acc[m][n] = zv; }

    for (int k0 = 0; k0 < Cn; k0 += 32) {
        __syncthreads();
        #pragma unroll
        for (int q = 0; q < 2; ++q) {
            const int tb = (q * 256 + t) * 16;
            const int rr = tb >> 6;     // tile row 0..127
            const int cb = tb & 63;     // byte within 64B row
            const size_t ga = (((size_t)(row0 + rr) * Cn + k0) << 1) + cb;
            const size_t gb = (((size_t)(col0 + rr) * Cn + k0) << 1) + cb;
            gl_lds16((const char*)Ahi + ga, sm + tb);
            gl_lds16((const char*)Alo + ga, sm + 8192 + tb);
            gl_lds16((const char*)Bhi + gb, sm + 16384 + tb);
            gl_lds16((const char*)Blo + gb, sm + 24576 + tb);
        }
        __syncthreads();

        bf16x8 ah[4], al[4], bh[4], bl[4];
        #pragma unroll
        for (int m = 0; m < 4; ++m) {
            const int rb = (wr + m * 16 + fr) * 64 + kb;
            ah[m] = *(const bf16x8*)(sm + rb);
            al[m] = *(const bf16x8*)(sm + 8192 + rb);
        }
        #pragma unroll
        for (int n = 0; n < 4; ++n) {
            const int rb = (wc + n * 16 + fr) * 64 + kb;
            bh[n] = *(const bf16x8*)(sm + 16384 + rb);
            bl[n] = *(const bf16x8*)(sm + 24576 + rb);
        }
        #pragma unroll
        for (int m = 0; m < 4; ++m)
            #pragma unroll
            for (int n = 0; n < 4; ++n) {
                acc[m][n] = __builtin_amdgcn_mfma_f32_16x16x32_bf16(ah[m], bh[n], acc[m][n], 0, 0, 0);
                acc[m][n] = __builtin_amdgcn_mfma_f32_16x16x32_bf16(ah[m], bl[n], acc[m][n], 0, 0, 0);
                acc[m][n] = __builtin_amdgcn_mfma_f32_16x16x32_bf16(al[m], bh[n], acc[m][n], 0, 0, 0);
            }
    }

    const int orow = row0 + wr + (lane >> 4) * 4;
    const int ocol = col0 + wc + fr;
    #pragma unroll
    for (int m = 0; m < 4; ++m)
        #pragma unroll
        for (int n = 0; n < 4; ++n)
            #pragma unroll
            for (int q2 = 0; q2 < 4; ++q2)
                Cout[(size_t)(orow + m * 16 + q2) * Cn + ocol + n * 16] = acc[m][n][q2];
}

// ---------- kernel 4: state update + out einsum + groupnorm + GLU ----------
// grid 2048, block 256 ; 16 (b,h) pairs per block, 16 lanes per pair, float4 on m
__global__ __launch_bounds__(256) void k_state(
    const float* __restrict__ rbuf, const float* __restrict__ kbuf,
    const float* __restrict__ vbuf, const float* __restrict__ gbuf,
    const float* __restrict__ wdec, const float* __restrict__ state,
    const float* __restrict__ tfaa, const float* __restrict__ gsc,
    const float* __restrict__ gbi, float* __restrict__ new_state,
    u16* __restrict__ Ghi, u16* __restrict__ Glo)
{
    __shared__ float rL[1024], kL[1024], wL[1024], tL[1024];
    const int t = threadIdx.x;
    const int bh0 = blockIdx.x * 16;
    {
        const size_t base = (size_t)bh0 * 64 + t * 4;
        *(float4*)&rL[t * 4] = *(const float4*)&rbuf[base];
        *(float4*)&kL[t * 4] = *(const float4*)&kbuf[base];
        *(float4*)&wL[t * 4] = *(const float4*)&wdec[base];
    }
    for (int i = t; i < 1024; i += 256) {
        const int g = i >> 6, h = (bh0 + g) & 31;
        tL[i] = tfaa[h * 64 + (i & 63)];
    }
    __syncthreads();

    const int g = t >> 4, ln = t & 15;
    const int bh = bh0 + g;
    const float4 v4 = *(const float4*)&vbuf[(size_t)bh * 64 + ln * 4];
    const float* sp = state + (size_t)bh * 4096 + ln * 4;
    float* np = new_state + (size_t)bh * 4096 + ln * 4;
    float ox = 0, oy = 0, oz = 0, ow = 0;
    #pragma unroll 4
    for (int n = 0; n < 64; ++n) {
        const float4 s4 = *(const float4*)(sp + (size_t)n * 64);
        const float kn = kL[g * 64 + n], rn = rL[g * 64 + n];
        const float wn = wL[g * 64 + n], tn = tL[g * 64 + n];
        const float ax = kn * v4.x, ay = kn * v4.y, az = kn * v4.z, aw = kn * v4.w;
        ox += rn * (tn * ax + s4.x); oy += rn * (tn * ay + s4.y);
        oz += rn * (tn * az + s4.z); ow += rn * (tn * aw + s4.w);
        float4 ns;
        ns.x = ax + wn * s4.x; ns.y = ay + wn * s4.y;
        ns.z = az + wn * s4.z; ns.w = aw + wn * s4.w;
        *(float4*)(np + (size_t)n * 64) = ns;
    }
    // groupnorm over the 16-lane group (64 channels)
    float s1 = ox + oy + oz + ow;
    #pragma unroll
    for (int m = 1; m < 16; m <<= 1) s1 += __shfl_xor(s1, m, 64);
    const float mu = s1 * (1.f / 64.f);
    const float dx = ox - mu, dy = oy - mu, dz = oz - mu, dw = ow - mu;
    float s2 = dx * dx + dy * dy + dz * dz + dw * dw;
    #pragma unroll
    for (int m = 1; m < 16; m <<= 1) s2 += __shfl_xor(s2, m, 64);
    const float rs = rsqrtf(s2 * (1.f / 64.f) + 6.4e-4f);

    const int h = bh & 31;
    const int cix = h * 64 + ln * 4;
    const float4 sc4 = *(const float4*)&gsc[cix];
    const float4 bi4 = *(const float4*)&gbi[cix];
    const float4 g4 = *(const float4*)&gbuf[(size_t)bh * 64 + ln * 4];
    float q[4] = {dx * rs * sc4.x + bi4.x, dy * rs * sc4.y + bi4.y,
                  dz * rs * sc4.z + bi4.z, dw * rs * sc4.w + bi4.w};
    float gv[4] = {g4.x, g4.y, g4.z, g4.w};
    u16 hh[4], ll[4];
    #pragma unroll
    for (int i = 0; i < 4; ++i) {
        float glu = gv[i] / (1.f + expf(-gv[i]));   // g*sigmoid(g)
        splitf(q[i] * glu, hh[i], ll[i]);
    }
    const size_t go = (size_t)bh * 64 + ln * 4;
    unsigned long long ph = (unsigned long long)hh[0] | ((unsigned long long)hh[1] << 16) |
                            ((unsigned long long)hh[2] << 32) | ((unsigned long long)hh[3] << 48);
    unsigned long long pl = (unsigned long long)ll[0] | ((unsigned long long)ll[1] << 16) |
                            ((unsigned long long)ll[2] << 32) | ((unsigned long long)ll[3] << 48);
    *(unsigned long long*)&Ghi[go] = ph;
    *(unsigned long long*)&Glo[go] = pl;
}

// ---------- host ----------
extern "C" void kernel_launch(void* const* d_in, const int* in_sizes, int n_in,
                              void* d_out, int out_size, void* d_ws, size_t ws_size,
                              hipStream_t stream)
{
    (void)in_sizes; (void)n_in; (void)out_size;
    const float* inputs  = (const float*)d_in[0];
    const float* shifted = (const float*)d_in[1];
    const float* state   = (const float*)d_in[2];
    const float* tmx     = (const float*)d_in[3];
    const float* w1      = (const float*)d_in[4];
    const float* w2      = (const float*)d_in[5];
    const float* wkvrg   = (const float*)d_in[6];
    const float* wrkvg   = (const float*)d_in[7];
    const float* tdw1    = (const float*)d_in[8];
    const float* tdw2    = (const float*)d_in[9];
    const float* tdp     = (const float*)d_in[10];
    const float* tfaa    = (const float*)d_in[11];
    const float* gsc     = (const float*)d_in[12];
    const float* gbi     = (const float*)d_in[13];
    const float* wout    = (const float*)d_in[14];

    float* out_f       = (float*)d_out;
    float* new_shifted = out_f + BC;
    float* new_state   = out_f + 2 * BC;

    char* ws = (char*)d_ws;
    u16*   Ahi  = (u16*)(ws);                               // 16 MB
    u16*   Alo  = (u16*)(ws + ((size_t)16 << 20));          // 16 MB
    float* wdec = (float*)(ws + ((size_t)32 << 20));        // 8 MB
    float* rkvg = (float*)(ws + ((size_t)40 << 20));        // 32 MB
    u16*   WThi = (u16*)(ws + ((size_t)72 << 20));
    u16*   Ghi  = (u16*)(ws);                               // reuse A region
    u16*   Glo  = (u16*)(ws + ((size_t)16 << 20));

    const bool big = ws_size >= ((size_t)104 << 20);
    u16* WTlo = big ? (u16*)(ws + ((size_t)88 << 20))       // 2 slots each
                    : (u16*)(ws + ((size_t)80 << 20));      // 1 slot

    k_prep<<<dim3(256), dim3(256), 0, stream>>>(
        inputs, shifted, tmx, w1, w2, wkvrg, tdw1, tdw2, tdp,
        new_shifted, Ahi, Alo, wdec);

    if (big) {
        for (int pair = 0; pair < 2; ++pair) {
            for (int s = 0; s < 2; ++s) {
                int f = pair * 2 + s;
                k_transpose_split<<<dim3(64, 64), dim3(32, 8), 0, stream>>>(
                    wrkvg + (size_t)f * CC, WThi + (size_t)s * CC, WTlo + (size_t)s * CC);
            }
            k_gemm<<<dim3(16, 8, 2), dim3(256), 0, stream>>>(
                Ahi + (size_t)pair * 2 * BC, Alo + (size_t)pair * 2 * BC,
                WThi, WTlo, rkvg + (size_t)pair * 2 * BC,
                (unsigned long long)BC, (unsigned long long)CC, (unsigned long long)BC);
        }
    } else {
        for (int f = 0; f < 4; ++f) {
            k_transpose_split<<<dim3(64, 64), dim3(32, 8), 0, stream>>>(
                wrkvg + (size_t)f * CC, WThi, WTlo);
            k_gemm<<<dim3(16, 8, 1), dim3(256), 0, stream>>>(
                Ahi + (size_t)f * BC, Alo + (size_t)f * BC,
                WThi, WTlo, rkvg + (size_t)f * BC, 0ULL, 0ULL, 0ULL);
        }
    }

    k_state<<<dim3(2048), dim3(256), 0, stream>>>(
        rkvg, rkvg + BC, rkvg + 2 * BC, rkvg + 3 * BC,
        wdec, state, tfaa, gsc, gbi, new_state, Ghi, Glo);

    k_transpose_split<<<dim3(64, 64), dim3(32, 8), 0, stream>>>(wout, WThi, WTlo);
    k_gemm<<<dim3(16, 8, 1), dim3(256), 0, stream>>>(
        Ghi, Glo, WThi, WTlo, out_f, 0ULL, 0ULL, 0ULL);
}